// Round 4
// baseline (681.487 us; speedup 1.0000x reference)
//
#include <hip/hip_runtime.h>
#include <type_traits>
#include <utility>

#define B_ 4
#define T_ 160
#define S_ 80
#define F_ 640
#define H_ 1024
#define V_ 1024

typedef float f32x4 __attribute__((ext_vector_type(4)));
typedef short s16x8 __attribute__((ext_vector_type(8)));
typedef __bf16 bf16x8_t __attribute__((ext_vector_type(8)));

// ---- MFMA wrapper: hedge between V8s (short) and V8y (__bf16) builtin signatures ----
template <typename T, typename = void>
struct MfmaTakes : std::false_type {};
template <typename T>
struct MfmaTakes<T, std::void_t<decltype(__builtin_amdgcn_mfma_f32_16x16x32_bf16(
    std::declval<T>(), std::declval<T>(), std::declval<f32x4>(), 0, 0, 0))>>
    : std::true_type {};

template <typename S8>
__device__ __forceinline__ f32x4 mfma_bf16_16x16x32(S8 a, S8 b, f32x4 c) {
  if constexpr (MfmaTakes<S8>::value) {
    return __builtin_amdgcn_mfma_f32_16x16x32_bf16(a, b, c, 0, 0, 0);
  } else {
    return __builtin_amdgcn_mfma_f32_16x16x32_bf16(
        __builtin_bit_cast(bf16x8_t, a), __builtin_bit_cast(bf16x8_t, b), c, 0, 0, 0);
  }
}

// fp32 -> bf16 round-to-nearest-even (no NaN in this workload)
__device__ __forceinline__ unsigned short f2bf(float x) {
  unsigned int u = __float_as_uint(x);
  u += 0x7FFFu + ((u >> 16) & 1u);
  return (unsigned short)(u >> 16);
}

// ---------------------------------------------------------------------------
// Kernel 1: cast W1,W2 to bf16 in fragment-contiguous layout [K/8][N][8]
// so a B-fragment for mfma_16x16x32 is one 16B global load.
// ---------------------------------------------------------------------------
__global__ __launch_bounds__(256) void prep_weights(const float* __restrict__ W1,
                                                    const float* __restrict__ W2,
                                                    s16x8* __restrict__ W1p,
                                                    s16x8* __restrict__ W2p) {
  const int NW1 = (F_ / 8) * H_;   // 81920 chunks
  const int NW2 = (H_ / 8) * V_;   // 131072 chunks
  int c = blockIdx.x * 256 + threadIdx.x;
  if (c < NW1) {
    int kg = c >> 10, v = c & 1023;
    s16x8 o;
#pragma unroll
    for (int i = 0; i < 8; ++i) o[i] = (short)f2bf(W1[(kg * 8 + i) * H_ + v]);
    W1p[c] = o;
  } else if (c < NW1 + NW2) {
    int c2 = c - NW1;
    int kg = c2 >> 10, v = c2 & 1023;
    s16x8 o;
#pragma unroll
    for (int i = 0; i < 8; ++i) o[i] = (short)f2bf(W2[(kg * 8 + i) * V_ + v]);
    W2p[c2] = o;
  }
}

// ---------------------------------------------------------------------------
// Kernel 2: P = src@W1 + b1 (640 rows), Q = tgt@W1 (320 rows), fp32 out.
// 15 WGs x 512 thr; BM=64, 8 waves col-split (128 cols each); bf16 MFMA.
// ---------------------------------------------------------------------------
__global__ __launch_bounds__(512, 2) void pq_gemm(const float* __restrict__ src,
                                                  const float* __restrict__ tgt,
                                                  const s16x8* __restrict__ W1p,
                                                  const float* __restrict__ b1,
                                                  float* __restrict__ P,
                                                  float* __restrict__ Q) {
  __shared__ s16x8 a_lds[64 * 80];  // 80 KB: rows m, 80 k-chunks, swizzled
  const int tid = threadIdx.x;
  const int wr = blockIdx.x;
  const int r0 = wr * 64;
  const bool isP = (wr < 10);  // rows 0..639 are src, 640..959 are tgt

  for (int c = tid; c < 64 * 80; c += 512) {
    int m = c / 80, kg8 = c - m * 80;
    int R = r0 + m;
    const float* rowp = isP ? (src + R * F_) : (tgt + (R - 640) * F_);
    const f32x4* p4 = (const f32x4*)(rowp + kg8 * 8);
    f32x4 x0 = p4[0], x1 = p4[1];
    s16x8 o;
#pragma unroll
    for (int i = 0; i < 4; ++i) o[i] = (short)f2bf(x0[i]);
#pragma unroll
    for (int i = 0; i < 4; ++i) o[4 + i] = (short)f2bf(x1[i]);
    a_lds[m * 80 + (kg8 ^ (m & 7))] = o;
  }
  __syncthreads();

  const int l = tid & 63, wv = tid >> 6;
  const int g = l >> 4, cl = l & 15;
  const f32x4 zero = {0.f, 0.f, 0.f, 0.f};
  f32x4 acc[4][8];
#pragma unroll
  for (int rt = 0; rt < 4; ++rt)
#pragma unroll
    for (int ct = 0; ct < 8; ++ct) acc[rt][ct] = zero;

  const s16x8* bbase = W1p + g * 1024 + wv * 128 + cl;
  s16x8 bA[8], bB[8], af[4];
#pragma unroll
  for (int ct = 0; ct < 8; ++ct) bA[ct] = bbase[ct * 16];

  for (int ks = 0; ks < 20; ks += 2) {
#pragma unroll
    for (int ct = 0; ct < 8; ++ct) bB[ct] = bbase[(ks + 1) * 4096 + ct * 16];
#pragma unroll
    for (int rt = 0; rt < 4; ++rt) {
      int m = rt * 16 + cl;
      af[rt] = a_lds[m * 80 + ((ks * 4 + g) ^ (m & 7))];
    }
#pragma unroll
    for (int ct = 0; ct < 8; ++ct)
#pragma unroll
      for (int rt = 0; rt < 4; ++rt)
        acc[rt][ct] = mfma_bf16_16x16x32(af[rt], bA[ct], acc[rt][ct]);
    int ksn = (ks + 2 < 20) ? (ks + 2) : 0;  // dummy reload on last iter
#pragma unroll
    for (int ct = 0; ct < 8; ++ct) bA[ct] = bbase[ksn * 4096 + ct * 16];
#pragma unroll
    for (int rt = 0; rt < 4; ++rt) {
      int m = rt * 16 + cl;
      af[rt] = a_lds[m * 80 + (((ks + 1) * 4 + g) ^ (m & 7))];
    }
#pragma unroll
    for (int ct = 0; ct < 8; ++ct)
#pragma unroll
      for (int rt = 0; rt < 4; ++rt)
        acc[rt][ct] = mfma_bf16_16x16x32(af[rt], bB[ct], acc[rt][ct]);
  }

  float b1v[8];
#pragma unroll
  for (int ct = 0; ct < 8; ++ct) b1v[ct] = isP ? b1[wv * 128 + ct * 16 + cl] : 0.f;
  float* outbase = isP ? P : Q;
  const int orow0 = isP ? r0 : (r0 - 640);
#pragma unroll
  for (int rt = 0; rt < 4; ++rt) {
#pragma unroll
    for (int j = 0; j < 4; ++j) {
      int row = rt * 16 + g * 4 + j;
      float* op = outbase + (size_t)(orow0 + row) * H_ + wv * 128 + cl;
#pragma unroll
      for (int ct = 0; ct < 8; ++ct) op[ct * 16] = acc[rt][ct][j] + b1v[ct];
    }
  }
}

// ---------------------------------------------------------------------------
// Kernel 3: fused h-build + GEMM2 + bias + log_softmax.
// 800 WGs x 1024 threads (16 waves). Tile: 64 rows (8t x 8s) x 1024 cols.
// Each wave owns 64 cols; acc[4][4] = 64 AGPR.
// REGISTER BUDGET (gfx950 unified VGPR+AGPR file): launch_bounds(1024,4)
// capped at 128 total regs/wave -> compiler SPILLED (R2/R3: +1.7 GB HBM
// scratch traffic, MfmaUtil 6.7%). (1024,3) gives ~170 regs/wave: 64 acc
// + 48 frags + ~40 temps fits with no spill, still 3 waves/SIMD.
// Stores NORMAL (cached): NT stores caused RMW amplification (R2).
// ---------------------------------------------------------------------------
__global__ __launch_bounds__(1024, 3) void joint_main(const float* __restrict__ Pm,
                                                      const float* __restrict__ Qm,
                                                      const s16x8* __restrict__ W2p,
                                                      const float* __restrict__ b2,
                                                      float* __restrict__ out) {
  __shared__ s16x8 h_lds[64 * 128];  // 128 KB
  const int tid = threadIdx.x;
  int bx = blockIdx.x;
  int bid = (bx & 7) * 100 + (bx >> 3);  // XCD-contiguous swizzle (800 % 8 == 0)
  const int b = bid / 200;
  int rem = bid - b * 200;
  const int t0 = (rem / 10) * 8;
  const int s0 = (rem - (rem / 10) * 10) * 8;

  // build h = relu(P[t] + Q[s]) as bf16, swizzled: chunk (m,kg8) -> slot kg8^(m&7)
  for (int c = tid; c < 64 * 128; c += 1024) {
    int m = c >> 7, kg8 = c & 127;
    int dt = m >> 3, ds = m & 7;
    const f32x4* p4 = (const f32x4*)(Pm + (size_t)(b * T_ + t0 + dt) * H_ + kg8 * 8);
    const f32x4* q4 = (const f32x4*)(Qm + (size_t)(b * S_ + s0 + ds) * H_ + kg8 * 8);
    f32x4 x0 = p4[0] + q4[0];
    f32x4 x1 = p4[1] + q4[1];
    s16x8 o;
#pragma unroll
    for (int i = 0; i < 4; ++i) o[i] = (short)f2bf(fmaxf(x0[i], 0.f));
#pragma unroll
    for (int i = 0; i < 4; ++i) o[4 + i] = (short)f2bf(fmaxf(x1[i], 0.f));
    h_lds[m * 128 + (kg8 ^ (m & 7))] = o;
  }
  __syncthreads();

  const int l = tid & 63, wv = tid >> 6;   // wv in 0..15, owns cols [wv*64, wv*64+64)
  const int g = l >> 4, cl = l & 15;
  const f32x4 zero = {0.f, 0.f, 0.f, 0.f};
  f32x4 acc[4][4];
#pragma unroll
  for (int rt = 0; rt < 4; ++rt)
#pragma unroll
    for (int ct = 0; ct < 4; ++ct) acc[rt][ct] = zero;

  const s16x8* bbase = W2p + g * 1024 + wv * 64 + cl;
  s16x8 bA[4], bB[4], af[4];
#pragma unroll
  for (int ct = 0; ct < 4; ++ct) bA[ct] = bbase[ct * 16];

  for (int ks = 0; ks < 32; ks += 2) {
#pragma unroll
    for (int ct = 0; ct < 4; ++ct) bB[ct] = bbase[(ks + 1) * 4096 + ct * 16];
#pragma unroll
    for (int rt = 0; rt < 4; ++rt) {
      int m = rt * 16 + cl;
      af[rt] = h_lds[m * 128 + ((ks * 4 + g) ^ (m & 7))];
    }
#pragma unroll
    for (int ct = 0; ct < 4; ++ct)
#pragma unroll
      for (int rt = 0; rt < 4; ++rt)
        acc[rt][ct] = mfma_bf16_16x16x32(af[rt], bA[ct], acc[rt][ct]);
    int ksn = (ks + 2 < 32) ? (ks + 2) : 0;  // dummy reload on last iter
#pragma unroll
    for (int ct = 0; ct < 4; ++ct) bA[ct] = bbase[ksn * 4096 + ct * 16];
#pragma unroll
    for (int rt = 0; rt < 4; ++rt) {
      int m = rt * 16 + cl;
      af[rt] = h_lds[m * 128 + (((ks + 1) * 4 + g) ^ (m & 7))];
    }
#pragma unroll
    for (int ct = 0; ct < 4; ++ct)
#pragma unroll
      for (int rt = 0; rt < 4; ++rt)
        acc[rt][ct] = mfma_bf16_16x16x32(af[rt], bB[ct], acc[rt][ct]);
  }

  // ---- epilogue: +b2, row-wise log_softmax across 16 waves, store ----
  __syncthreads();  // all waves done reading h before overlaying reductions
  float* redm = reinterpret_cast<float*>(h_lds);  // [16 waves][64 rows]
  float* reds = redm + 1024;                      // [16 waves][64 rows]

  float b2v[4];
#pragma unroll
  for (int ct = 0; ct < 4; ++ct) b2v[ct] = b2[wv * 64 + ct * 16 + cl];
#pragma unroll
  for (int rt = 0; rt < 4; ++rt)
#pragma unroll
    for (int ct = 0; ct < 4; ++ct)
#pragma unroll
      for (int j = 0; j < 4; ++j) acc[rt][ct][j] += b2v[ct];

  // per-row max over this wave's 64 cols (in-lane over ct, butterfly over 16 lanes)
#pragma unroll
  for (int rt = 0; rt < 4; ++rt)
#pragma unroll
    for (int j = 0; j < 4; ++j) {
      float mx = acc[rt][0][j];
#pragma unroll
      for (int ct = 1; ct < 4; ++ct) mx = fmaxf(mx, acc[rt][ct][j]);
#pragma unroll
      for (int msk = 1; msk < 16; msk <<= 1) mx = fmaxf(mx, __shfl_xor(mx, msk, 64));
      if (cl == 0) redm[wv * 64 + rt * 16 + g * 4 + j] = mx;
    }
  __syncthreads();

  float gm[4][4], ps[4][4];
#pragma unroll
  for (int rt = 0; rt < 4; ++rt)
#pragma unroll
    for (int j = 0; j < 4; ++j) {
      int row = rt * 16 + g * 4 + j;
      float mx = redm[row];
#pragma unroll
      for (int w = 1; w < 16; ++w) mx = fmaxf(mx, redm[w * 64 + row]);
      gm[rt][j] = mx;
      ps[rt][j] = 0.f;
    }
#pragma unroll
  for (int rt = 0; rt < 4; ++rt)
#pragma unroll
    for (int ct = 0; ct < 4; ++ct)
#pragma unroll
      for (int j = 0; j < 4; ++j) ps[rt][j] += __expf(acc[rt][ct][j] - gm[rt][j]);
#pragma unroll
  for (int rt = 0; rt < 4; ++rt)
#pragma unroll
    for (int j = 0; j < 4; ++j) {
#pragma unroll
      for (int msk = 1; msk < 16; msk <<= 1) ps[rt][j] += __shfl_xor(ps[rt][j], msk, 64);
      if (cl == 0) reds[wv * 64 + rt * 16 + g * 4 + j] = ps[rt][j];
    }
  __syncthreads();

#pragma unroll
  for (int rt = 0; rt < 4; ++rt)
#pragma unroll
    for (int j = 0; j < 4; ++j) {
      int row = rt * 16 + g * 4 + j;
      float s = reds[row];
#pragma unroll
      for (int w = 1; w < 16; ++w) s += reds[w * 64 + row];
      float lse = gm[rt][j] + __logf(s);
      int n = (b * T_ + t0 + (row >> 3)) * S_ + s0 + (row & 7);
      float* op = out + (size_t)n * V_ + wv * 64 + cl;
#pragma unroll
      for (int ct = 0; ct < 4; ++ct) op[ct * 16] = acc[rt][ct][j] - lse;
    }
}

// ---------------------------------------------------------------------------
extern "C" void kernel_launch(void* const* d_in, const int* in_sizes, int n_in,
                              void* d_out, int out_size, void* d_ws, size_t ws_size,
                              hipStream_t stream) {
  const float* src = (const float*)d_in[0];  // [4,160,640]
  const float* tgt = (const float*)d_in[1];  // [4,80,640]
  const float* W1  = (const float*)d_in[2];  // [640,1024]
  const float* b1  = (const float*)d_in[3];  // [1024]
  const float* W2  = (const float*)d_in[4];  // [1024,1024]
  const float* b2  = (const float*)d_in[5];  // [1024]
  float* out = (float*)d_out;

  char* ws = (char*)d_ws;
  s16x8* W1p = (s16x8*)(ws);             // 1,310,720 B
  s16x8* W2p = (s16x8*)(ws + 1310720);   // 2,097,152 B
  float* P   = (float*)(ws + 3407872);   // 2,621,440 B  (src@W1 + b1)
  float* Q   = (float*)(ws + 6029312);   // 1,310,720 B  (tgt@W1)
  // total ws use: 7,340,032 B

  prep_weights<<<832, 256, 0, stream>>>(W1, W2, W1p, W2p);
  pq_gemm<<<15, 512, 0, stream>>>(src, tgt, W1p, b1, P, Q);
  joint_main<<<800, 1024, 0, stream>>>(P, Q, W2p, b2, out);
}

// Round 5
// 220.864 us; speedup vs baseline: 3.0856x; 3.0856x over previous
//
#include <hip/hip_runtime.h>
#include <type_traits>
#include <utility>

#define B_ 4
#define T_ 160
#define S_ 80
#define F_ 640
#define H_ 1024
#define V_ 1024

typedef float f32x4 __attribute__((ext_vector_type(4)));
typedef short s16x8 __attribute__((ext_vector_type(8)));
typedef __bf16 bf16x8_t __attribute__((ext_vector_type(8)));

// ---- MFMA wrapper: hedge between V8s (short) and V8y (__bf16) builtin signatures ----
template <typename T, typename = void>
struct MfmaTakes : std::false_type {};
template <typename T>
struct MfmaTakes<T, std::void_t<decltype(__builtin_amdgcn_mfma_f32_16x16x32_bf16(
    std::declval<T>(), std::declval<T>(), std::declval<f32x4>(), 0, 0, 0))>>
    : std::true_type {};

template <typename S8>
__device__ __forceinline__ f32x4 mfma_bf16_16x16x32(S8 a, S8 b, f32x4 c) {
  if constexpr (MfmaTakes<S8>::value) {
    return __builtin_amdgcn_mfma_f32_16x16x32_bf16(a, b, c, 0, 0, 0);
  } else {
    return __builtin_amdgcn_mfma_f32_16x16x32_bf16(
        __builtin_bit_cast(bf16x8_t, a), __builtin_bit_cast(bf16x8_t, b), c, 0, 0, 0);
  }
}

// fp32 -> bf16 round-to-nearest-even (no NaN in this workload)
__device__ __forceinline__ unsigned short f2bf(float x) {
  unsigned int u = __float_as_uint(x);
  u += 0x7FFFu + ((u >> 16) & 1u);
  return (unsigned short)(u >> 16);
}

// ---------------------------------------------------------------------------
// Kernel 1: cast W1,W2 to bf16 in fragment-contiguous layout [K/8][N][8]
// so a B-fragment for mfma_16x16x32 is one 16B global load.
// ---------------------------------------------------------------------------
__global__ __launch_bounds__(256) void prep_weights(const float* __restrict__ W1,
                                                    const float* __restrict__ W2,
                                                    s16x8* __restrict__ W1p,
                                                    s16x8* __restrict__ W2p) {
  const int NW1 = (F_ / 8) * H_;   // 81920 chunks
  const int NW2 = (H_ / 8) * V_;   // 131072 chunks
  int c = blockIdx.x * 256 + threadIdx.x;
  if (c < NW1) {
    int kg = c >> 10, v = c & 1023;
    s16x8 o;
#pragma unroll
    for (int i = 0; i < 8; ++i) o[i] = (short)f2bf(W1[(kg * 8 + i) * H_ + v]);
    W1p[c] = o;
  } else if (c < NW1 + NW2) {
    int c2 = c - NW1;
    int kg = c2 >> 10, v = c2 & 1023;
    s16x8 o;
#pragma unroll
    for (int i = 0; i < 8; ++i) o[i] = (short)f2bf(W2[(kg * 8 + i) * V_ + v]);
    W2p[c2] = o;
  }
}

// ---------------------------------------------------------------------------
// Kernel 2: P = src@W1 + b1 (640 rows), Q = tgt@W1 (320 rows), fp32 out.
// 15 WGs x 512 thr; BM=64, 8 waves col-split (128 cols each); bf16 MFMA.
// ---------------------------------------------------------------------------
__global__ __launch_bounds__(512, 2) void pq_gemm(const float* __restrict__ src,
                                                  const float* __restrict__ tgt,
                                                  const s16x8* __restrict__ W1p,
                                                  const float* __restrict__ b1,
                                                  float* __restrict__ P,
                                                  float* __restrict__ Q) {
  __shared__ s16x8 a_lds[64 * 80];  // 80 KB: rows m, 80 k-chunks, swizzled
  const int tid = threadIdx.x;
  const int wr = blockIdx.x;
  const int r0 = wr * 64;
  const bool isP = (wr < 10);  // rows 0..639 are src, 640..959 are tgt

  for (int c = tid; c < 64 * 80; c += 512) {
    int m = c / 80, kg8 = c - m * 80;
    int R = r0 + m;
    const float* rowp = isP ? (src + R * F_) : (tgt + (R - 640) * F_);
    const f32x4* p4 = (const f32x4*)(rowp + kg8 * 8);
    f32x4 x0 = p4[0], x1 = p4[1];
    s16x8 o;
#pragma unroll
    for (int i = 0; i < 4; ++i) o[i] = (short)f2bf(x0[i]);
#pragma unroll
    for (int i = 0; i < 4; ++i) o[4 + i] = (short)f2bf(x1[i]);
    a_lds[m * 80 + (kg8 ^ (m & 7))] = o;
  }
  __syncthreads();

  const int l = tid & 63, wv = tid >> 6;
  const int g = l >> 4, cl = l & 15;
  const f32x4 zero = {0.f, 0.f, 0.f, 0.f};
  f32x4 acc[4][8];
#pragma unroll
  for (int rt = 0; rt < 4; ++rt)
#pragma unroll
    for (int ct = 0; ct < 8; ++ct) acc[rt][ct] = zero;

  const s16x8* bbase = W1p + g * 1024 + wv * 128 + cl;
  s16x8 bA[8], bB[8], af[4];
#pragma unroll
  for (int ct = 0; ct < 8; ++ct) bA[ct] = bbase[ct * 16];

  for (int ks = 0; ks < 20; ks += 2) {
#pragma unroll
    for (int ct = 0; ct < 8; ++ct) bB[ct] = bbase[(ks + 1) * 4096 + ct * 16];
#pragma unroll
    for (int rt = 0; rt < 4; ++rt) {
      int m = rt * 16 + cl;
      af[rt] = a_lds[m * 80 + ((ks * 4 + g) ^ (m & 7))];
    }
#pragma unroll
    for (int ct = 0; ct < 8; ++ct)
#pragma unroll
      for (int rt = 0; rt < 4; ++rt)
        acc[rt][ct] = mfma_bf16_16x16x32(af[rt], bA[ct], acc[rt][ct]);
    int ksn = (ks + 2 < 20) ? (ks + 2) : 0;  // dummy reload on last iter
#pragma unroll
    for (int ct = 0; ct < 8; ++ct) bA[ct] = bbase[ksn * 4096 + ct * 16];
#pragma unroll
    for (int rt = 0; rt < 4; ++rt) {
      int m = rt * 16 + cl;
      af[rt] = a_lds[m * 80 + (((ks + 1) * 4 + g) ^ (m & 7))];
    }
#pragma unroll
    for (int ct = 0; ct < 8; ++ct)
#pragma unroll
      for (int rt = 0; rt < 4; ++rt)
        acc[rt][ct] = mfma_bf16_16x16x32(af[rt], bB[ct], acc[rt][ct]);
  }

  float b1v[8];
#pragma unroll
  for (int ct = 0; ct < 8; ++ct) b1v[ct] = isP ? b1[wv * 128 + ct * 16 + cl] : 0.f;
  float* outbase = isP ? P : Q;
  const int orow0 = isP ? r0 : (r0 - 640);
#pragma unroll
  for (int rt = 0; rt < 4; ++rt) {
#pragma unroll
    for (int j = 0; j < 4; ++j) {
      int row = rt * 16 + g * 4 + j;
      float* op = outbase + (size_t)(orow0 + row) * H_ + wv * 128 + cl;
#pragma unroll
      for (int ct = 0; ct < 8; ++ct) op[ct * 16] = acc[rt][ct][j] + b1v[ct];
    }
  }
}

// ---------------------------------------------------------------------------
// Kernel 3: fused h-build + GEMM2 + bias + log_softmax.
// 800 WGs x 1024 threads (16 waves), 64-row x 1024-col tile, wave owns 64 cols.
// REGISTER BUDGET: 1024-thr WG + 128 KB LDS forces 1 WG/CU = 4 waves/SIMD
// = hard cap 128 regs/wave (unified VGPR+AGPR). R2-R4 spilled (~1.7 GB HBM
// scratch, MfmaUtil 6.7%) because double-buffer frags + gm/ps[4][4] arrays
// pushed ~170. This version: simple K-loop (unroll 2, compiler-pipelined)
// and a scalar-only epilogue (lse finalized in LDS by 64 threads) so peak
// = 64 AGPR acc + ~50 VGPR < 128. No launch-bounds trickery can change the
// cap, only demand reduction.
// ---------------------------------------------------------------------------
__global__ __launch_bounds__(1024, 4) void joint_main(const float* __restrict__ Pm,
                                                      const float* __restrict__ Qm,
                                                      const s16x8* __restrict__ W2p,
                                                      const float* __restrict__ b2,
                                                      float* __restrict__ out) {
  __shared__ s16x8 h_lds[64 * 128];  // 128 KB
  const int tid = threadIdx.x;
  int bx = blockIdx.x;
  int bid = (bx & 7) * 100 + (bx >> 3);  // XCD-contiguous swizzle (800 % 8 == 0)
  const int b = bid / 200;
  int rem = bid - b * 200;
  const int t0 = (rem / 10) * 8;
  const int s0 = (rem - (rem / 10) * 10) * 8;

  // build h = relu(P[t] + Q[s]) as bf16, swizzled: chunk (m,kg8) -> slot kg8^(m&7)
  for (int c = tid; c < 64 * 128; c += 1024) {
    int m = c >> 7, kg8 = c & 127;
    int dt = m >> 3, ds = m & 7;
    const f32x4* p4 = (const f32x4*)(Pm + (size_t)(b * T_ + t0 + dt) * H_ + kg8 * 8);
    const f32x4* q4 = (const f32x4*)(Qm + (size_t)(b * S_ + s0 + ds) * H_ + kg8 * 8);
    f32x4 x0 = p4[0] + q4[0];
    f32x4 x1 = p4[1] + q4[1];
    s16x8 o;
#pragma unroll
    for (int i = 0; i < 4; ++i) o[i] = (short)f2bf(fmaxf(x0[i], 0.f));
#pragma unroll
    for (int i = 0; i < 4; ++i) o[4 + i] = (short)f2bf(fmaxf(x1[i], 0.f));
    h_lds[m * 128 + (kg8 ^ (m & 7))] = o;
  }
  __syncthreads();

  const int l = tid & 63, wv = tid >> 6;   // wv in 0..15, owns cols [wv*64, wv*64+64)
  const int g = l >> 4, cl = l & 15;
  const f32x4 zero = {0.f, 0.f, 0.f, 0.f};
  f32x4 acc[4][4];
#pragma unroll
  for (int rt = 0; rt < 4; ++rt)
#pragma unroll
    for (int ct = 0; ct < 4; ++ct) acc[rt][ct] = zero;

  const s16x8* bbase = W2p + g * 1024 + wv * 64 + cl;

#pragma unroll 2
  for (int ks = 0; ks < 32; ++ks) {
    s16x8 b0 = bbase[ks * 4096];
    s16x8 b1f = bbase[ks * 4096 + 16];
    s16x8 b2f = bbase[ks * 4096 + 32];
    s16x8 b3f = bbase[ks * 4096 + 48];
    int m0 = cl, m1 = 16 + cl, m2 = 32 + cl, m3 = 48 + cl;
    int kc = ks * 4 + g;
    s16x8 a0 = h_lds[m0 * 128 + (kc ^ (m0 & 7))];
    s16x8 a1 = h_lds[m1 * 128 + (kc ^ (m1 & 7))];
    s16x8 a2 = h_lds[m2 * 128 + (kc ^ (m2 & 7))];
    s16x8 a3 = h_lds[m3 * 128 + (kc ^ (m3 & 7))];
    acc[0][0] = mfma_bf16_16x16x32(a0, b0, acc[0][0]);
    acc[1][0] = mfma_bf16_16x16x32(a1, b0, acc[1][0]);
    acc[2][0] = mfma_bf16_16x16x32(a2, b0, acc[2][0]);
    acc[3][0] = mfma_bf16_16x16x32(a3, b0, acc[3][0]);
    acc[0][1] = mfma_bf16_16x16x32(a0, b1f, acc[0][1]);
    acc[1][1] = mfma_bf16_16x16x32(a1, b1f, acc[1][1]);
    acc[2][1] = mfma_bf16_16x16x32(a2, b1f, acc[2][1]);
    acc[3][1] = mfma_bf16_16x16x32(a3, b1f, acc[3][1]);
    acc[0][2] = mfma_bf16_16x16x32(a0, b2f, acc[0][2]);
    acc[1][2] = mfma_bf16_16x16x32(a1, b2f, acc[1][2]);
    acc[2][2] = mfma_bf16_16x16x32(a2, b2f, acc[2][2]);
    acc[3][2] = mfma_bf16_16x16x32(a3, b2f, acc[3][2]);
    acc[0][3] = mfma_bf16_16x16x32(a0, b3f, acc[0][3]);
    acc[1][3] = mfma_bf16_16x16x32(a1, b3f, acc[1][3]);
    acc[2][3] = mfma_bf16_16x16x32(a2, b3f, acc[2][3]);
    acc[3][3] = mfma_bf16_16x16x32(a3, b3f, acc[3][3]);
  }

  // ---- epilogue: +b2, row-wise log_softmax across 16 waves, store ----
  __syncthreads();  // all waves done reading h before overlaying reductions
  float* redm = reinterpret_cast<float*>(h_lds);  // [16 waves][64 rows]
  float* reds = redm + 1024;                      // [16 waves][64 rows]
  float* lsebuf = reds + 1024;                    // [64 rows]

  // bias (4 scalars, then folded into acc)
#pragma unroll
  for (int ct = 0; ct < 4; ++ct) {
    float bv = b2[wv * 64 + ct * 16 + cl];
#pragma unroll
    for (int rt = 0; rt < 4; ++rt)
#pragma unroll
      for (int j = 0; j < 4; ++j) acc[rt][ct][j] += bv;
  }

  // per-wave per-row max -> redm  (scalars only, one row at a time)
#pragma unroll
  for (int rt = 0; rt < 4; ++rt)
#pragma unroll
    for (int j = 0; j < 4; ++j) {
      float mx = fmaxf(fmaxf(acc[rt][0][j], acc[rt][1][j]),
                       fmaxf(acc[rt][2][j], acc[rt][3][j]));
#pragma unroll
      for (int msk = 1; msk < 16; msk <<= 1) mx = fmaxf(mx, __shfl_xor(mx, msk, 64));
      if (cl == 0) redm[wv * 64 + rt * 16 + g * 4 + j] = mx;
    }
  __syncthreads();

  // per-wave per-row partial sumexp vs global max -> reds (scalars only)
#pragma unroll
  for (int rt = 0; rt < 4; ++rt)
#pragma unroll
    for (int j = 0; j < 4; ++j) {
      int row = rt * 16 + g * 4 + j;
      float gm = redm[row];
#pragma unroll
      for (int w = 1; w < 16; ++w) gm = fmaxf(gm, redm[w * 64 + row]);
      float ps = __expf(acc[rt][0][j] - gm) + __expf(acc[rt][1][j] - gm) +
                 __expf(acc[rt][2][j] - gm) + __expf(acc[rt][3][j] - gm);
#pragma unroll
      for (int msk = 1; msk < 16; msk <<= 1) ps += __shfl_xor(ps, msk, 64);
      if (cl == 0) reds[wv * 64 + rt * 16 + g * 4 + j] = ps;
    }
  __syncthreads();

  // finalize lse per row (threads 0..63)
  if (tid < 64) {
    int row = tid;
    float gm = redm[row], s = 0.f;
#pragma unroll
    for (int w = 1; w < 16; ++w) gm = fmaxf(gm, redm[w * 64 + row]);
#pragma unroll
    for (int w = 0; w < 16; ++w) s += reds[w * 64 + row];
    lsebuf[row] = gm + __logf(s);
  }
  __syncthreads();

  // store
#pragma unroll
  for (int rt = 0; rt < 4; ++rt)
#pragma unroll
    for (int j = 0; j < 4; ++j) {
      int row = rt * 16 + g * 4 + j;
      float lse = lsebuf[row];
      int n = (b * T_ + t0 + (row >> 3)) * S_ + s0 + (row & 7);
      float* op = out + (size_t)n * V_ + wv * 64 + cl;
#pragma unroll
      for (int ct = 0; ct < 4; ++ct) op[ct * 16] = acc[rt][ct][j] - lse;
    }
}

// ---------------------------------------------------------------------------
extern "C" void kernel_launch(void* const* d_in, const int* in_sizes, int n_in,
                              void* d_out, int out_size, void* d_ws, size_t ws_size,
                              hipStream_t stream) {
  const float* src = (const float*)d_in[0];  // [4,160,640]
  const float* tgt = (const float*)d_in[1];  // [4,80,640]
  const float* W1  = (const float*)d_in[2];  // [640,1024]
  const float* b1  = (const float*)d_in[3];  // [1024]
  const float* W2  = (const float*)d_in[4];  // [1024,1024]
  const float* b2  = (const float*)d_in[5];  // [1024]
  float* out = (float*)d_out;

  char* ws = (char*)d_ws;
  s16x8* W1p = (s16x8*)(ws);             // 1,310,720 B
  s16x8* W2p = (s16x8*)(ws + 1310720);   // 2,097,152 B
  float* P   = (float*)(ws + 3407872);   // 2,621,440 B  (src@W1 + b1)
  float* Q   = (float*)(ws + 6029312);   // 1,310,720 B  (tgt@W1)
  // total ws use: 7,340,032 B

  prep_weights<<<832, 256, 0, stream>>>(W1, W2, W1p, W2p);
  pq_gemm<<<15, 512, 0, stream>>>(src, tgt, W1p, b1, P, Q);
  joint_main<<<800, 1024, 0, stream>>>(P, Q, W2p, b2, out);
}